// Round 1
// 592.296 us; speedup vs baseline: 2.7642x; 2.7642x over previous
//
#include <hip/hip_runtime.h>
#include <hip/hip_bf16.h>
#include <hip/hip_fp16.h>

#define NPOINTS 2048
#define BATCH   2
#define DIM     256
#define D2      128
#define D4      64
#define NHEAD   8
#define HDIM    32
#define KNNK    64
#define NROWS   (BATCH*NPOINTS)
#define SCALE_F 0.17677669529663687f

typedef unsigned short u16;

__device__ __forceinline__ float b2f(u16 u) { return __uint_as_float(((unsigned)u) << 16); }
__device__ __forceinline__ u16 f2b(float f) {
  __hip_bfloat16 h = __float2bfloat16(f);
  u16 r; __builtin_memcpy(&r, &h, 2); return r;
}

// ---------------------------------------------------------------------------
// Kernel 1: exact KNN (64 smallest of 2048) per point. Unchanged except the
// distance output is stored f16 (feeds only the distance-MLP; 5e-4 rel err).
// ---------------------------------------------------------------------------
__global__ __launch_bounds__(256) void knn_kernel(
    const float* __restrict__ xyz,
    int*    __restrict__ knn_idx,
    __half* __restrict__ knn_dist)
{
  __shared__ float dist[NPOINTS];
  __shared__ unsigned hist[256];
  __shared__ unsigned sh_sel, sh_below;

  const int bp = blockIdx.x;
  const int b  = bp >> 11;
  const int n  = bp & (NPOINTS - 1);
  const int t  = threadIdx.x;
  const float* P = xyz + (size_t)b * NPOINTS * 3;

  const float qx = P[n*3+0], qy = P[n*3+1], qz = P[n*3+2];
  const float r2n = qx*qx + qy*qy + qz*qz;
  for (int m = t; m < NPOINTS; m += 256) {
    float x = P[m*3+0], y = P[m*3+1], z = P[m*3+2];
    float r2m = x*x + y*y + z*z;
    float dt  = x*qx + y*qy + z*qz;
    float sq  = r2n + r2m - 2.f*dt;
    sq = fmaxf(sq, 0.f);
    dist[m] = (sq > 0.f) ? sqrtf(sq) : 0.f;
  }
  __syncthreads();

  unsigned prefix = 0u;
  int k_need = KNNK;
  for (int pass = 0; pass < 4; ++pass) {
    const int shift = 24 - pass*8;
    hist[t] = 0u;
    __syncthreads();
    for (int m = t; m < NPOINTS; m += 256) {
      unsigned bits = __float_as_uint(dist[m]);
      if (((bits >> shift) >> 8) == prefix)
        atomicAdd(&hist[(bits >> shift) & 255u], 1u);
    }
    __syncthreads();
    if (t < 64) {
      unsigned s0 = hist[t*4+0], s1 = hist[t*4+1], s2 = hist[t*4+2], s3 = hist[t*4+3];
      unsigned lsum = s0 + s1 + s2 + s3;
      unsigned scan = lsum;
      #pragma unroll
      for (int off = 1; off < 64; off <<= 1) {
        unsigned o = __shfl_up(scan, off);
        if (t >= off) scan += o;
      }
      unsigned excl = scan - lsum;
      unsigned kk = (unsigned)k_need;
      if (excl < kk && kk <= excl + lsum) {
        unsigned below = excl; int bin = t*4;
        if (kk > below + s0) { below += s0; bin++;
          if (kk > below + s1) { below += s1; bin++;
            if (kk > below + s2) { below += s2; bin++; } } }
        sh_sel = (unsigned)bin; sh_below = below;
      }
    }
    __syncthreads();
    prefix = (prefix << 8) | sh_sel;
    k_need -= (int)sh_below;
    __syncthreads();
  }
  const unsigned Tbits = prefix;
  const int base = KNNK - k_need;

  if (t < 64) {
    int*    oi = knn_idx  + (size_t)bp * KNNK;
    __half* od = knn_dist + (size_t)bp * KNNK;
    int taken = 0;
    for (int c = 0; c < NPOINTS/64; ++c) {
      int m = c*64 + t;
      float dv = dist[m];
      bool lt = (__float_as_uint(dv) < Tbits);
      unsigned long long msk = __ballot(lt);
      int off = __popcll(msk & ((1ull << t) - 1ull));
      if (lt) { oi[taken+off] = m; od[taken+off] = __float2half(dv); }
      taken += __popcll(msk);
    }
    int eq = 0;
    for (int c = 0; c < NPOINTS/64 && eq < k_need; ++c) {
      int m = c*64 + t;
      float dv = dist[m];
      bool e = (__float_as_uint(dv) == Tbits);
      unsigned long long msk = __ballot(e);
      int off = __popcll(msk & ((1ull << t) - 1ull));
      if (e && (eq + off) < k_need) { oi[base+eq+off] = m; od[base+eq+off] = __float2half(dv); }
      eq += __popcll(msk);
    }
  }
}

// ---------------------------------------------------------------------------
// Kernel 2: weight prep — bf16 (transposed where needed) copies into ws.
//   wkT[d][c] = wk[c][d]   (for coalesced g-fold reads)
//   w3T[c][j] = de_w3[j][c] (for coalesced w3@g reads)
//   wvB[c][d] = wv[c][d]   (bf16 cast only)
// ---------------------------------------------------------------------------
__global__ __launch_bounds__(256) void prep_kernel(
    const float* __restrict__ wk, const float* __restrict__ de_w3,
    const float* __restrict__ wv,
    u16* __restrict__ wkT, u16* __restrict__ w3T, u16* __restrict__ wvB)
{
  int tid = blockIdx.x*256 + threadIdx.x;
  if (tid < 65536) {
    int d = tid >> 8, c = tid & 255;
    wkT[tid] = f2b(wk[c*DIM + d]);
  } else if (tid < 98304) {
    int o = tid - 65536; int c = o >> 7, j = o & 127;
    w3T[o] = f2b(de_w3[j*DIM + c]);
  } else if (tid < 163840) {
    int o = tid - 98304;
    wvB[o] = f2b(wv[o]);
  }
}

// ---------------------------------------------------------------------------
// Kernel 3: batched q projection, 16 rows/block (weights amortized 16x).
// Writes q into d_out (scratch; overwritten row-locally later).
// ---------------------------------------------------------------------------
__global__ __launch_bounds__(256) void qproj_kernel(
    const float* __restrict__ features, const float* __restrict__ wq,
    const float* __restrict__ bq, float* __restrict__ qout)
{
  __shared__ __align__(16) float sf[16][DIM];
  const int r0 = blockIdx.x * 16, t = threadIdx.x;
  for (int r = 0; r < 16; ++r) sf[r][t] = features[(size_t)(r0+r)*DIM + t];
  __syncthreads();
  float acc[16];
  const float bqv = bq[t];
  #pragma unroll
  for (int r = 0; r < 16; ++r) acc[r] = bqv;
  for (int d = 0; d < DIM; d += 4) {
    float w0 = wq[(d+0)*DIM+t], w1 = wq[(d+1)*DIM+t];
    float w2 = wq[(d+2)*DIM+t], w3v = wq[(d+3)*DIM+t];
    #pragma unroll
    for (int r = 0; r < 16; ++r) {
      float4 f4 = *(const float4*)&sf[r][d];
      acc[r] = fmaf(f4.x, w0, acc[r]); acc[r] = fmaf(f4.y, w1, acc[r]);
      acc[r] = fmaf(f4.z, w2, acc[r]); acc[r] = fmaf(f4.w, w3v, acc[r]);
    }
  }
  #pragma unroll
  for (int r = 0; r < 16; ++r) qout[(size_t)(r0+r)*DIM + t] = acc[r];
}

// ---------------------------------------------------------------------------
// Kernel 4: fused per-point pipeline with K/V projections folded out.
//   g[c][h]   = sum_{d in head h} wk[c][d] q[d]            (wk-fold)
//   w3g[h][j] = sum_c de_w3[j][c] g[c][h]                  (w3-fold)
//   scores    = (F@g + h2@w3g + b3@g + q.bk) * SCALE
//   m[h][c]   = attn@F + (attn@h2)@w3 + b3    (sum attn = 1)
//   ctx       = m @ wv + bv                   -> d_out row (over q)
// F (gathered neighbor feats) and h2 are bf16 in LDS with XOR swizzle on the
// 16B-chunk index to kill the row-strided bank conflicts.
// ---------------------------------------------------------------------------
__global__ __launch_bounds__(256) void fused_kernel(
    const float* __restrict__ features,
    float* qctx,                       // d_out: q in, ctx out (row-local)
    const int*    __restrict__ knn_idx,
    const __half* __restrict__ knn_dist,
    const u16* __restrict__ wkT, const u16* __restrict__ w3T,
    const u16* __restrict__ wvB,
    const float* __restrict__ de_w1, const float* __restrict__ de_b1,
    const float* __restrict__ de_w2, const float* __restrict__ de_b2,
    const float* __restrict__ de_w3, const float* __restrict__ de_b3,
    const float* __restrict__ bk,    const float* __restrict__ bv)
{
  // 76.3 KB total -> 2 blocks/CU
  __shared__ __align__(16) u16   s_F [KNNK*DIM];   // 32KB; first 16KB = h1f f32[64][64]
  __shared__ __align__(16) u16   s_h2[KNNK*D2];    // 16KB bf16 swizzled
  __shared__ __align__(16) float s_gh[NHEAD*DIM];  // 8KB g[h][c]; later m[h][c]
  __shared__ __align__(16) float s_gc[DIM*NHEAD];  // 8KB g[c][h]
  __shared__ __align__(16) float s_w3g[NHEAD*D2];  // 4KB w3g[h][j]; later ah2T[j][h]
  __shared__ __align__(16) float s_sc[NHEAD*KNNK]; // 2KB scores
  __shared__ __align__(16) float s_aT[KNNK*NHEAD]; // 2KB attn transposed
  __shared__ __align__(16) float s_qv[DIM];
  __shared__ int   s_nidx[KNNK];
  __shared__ float s_ndist[KNNK];
  __shared__ float s_sb[NHEAD];

  float* h1f = (float*)s_F;

  const int bp = blockIdx.x;
  const int b  = bp >> 11;
  const int n  = bp & (NPOINTS - 1);
  const int t  = threadIdx.x;
  const float* featB = features + (size_t)b * NPOINTS * DIM;

  // P0
  if (t < KNNK) {
    s_nidx[t]  = knn_idx[(size_t)bp*KNNK + t];
    s_ndist[t] = __half2float(knn_dist[(size_t)bp*KNNK + t]);
  }
  s_qv[t] = qctx[(size_t)bp*DIM + t];
  __syncthreads();

  // P2: g (wk-fold), h1, and s0[h] = q.bk
  {
    float acc8[8];
    #pragma unroll
    for (int h = 0; h < 8; ++h) acc8[h] = 0.f;
    #pragma unroll
    for (int h = 0; h < 8; ++h) {
      #pragma unroll
      for (int dd = 0; dd < 32; dd += 4) {
        const int d = h*32 + dd;
        float4 q4 = *(const float4*)&s_qv[d];
        acc8[h] = fmaf(b2f(wkT[(d+0)*DIM + t]), q4.x, acc8[h]);
        acc8[h] = fmaf(b2f(wkT[(d+1)*DIM + t]), q4.y, acc8[h]);
        acc8[h] = fmaf(b2f(wkT[(d+2)*DIM + t]), q4.z, acc8[h]);
        acc8[h] = fmaf(b2f(wkT[(d+3)*DIM + t]), q4.w, acc8[h]);
      }
    }
    #pragma unroll
    for (int h = 0; h < 8; ++h) s_gh[h*DIM + t] = acc8[h];
    *(float4*)&s_gc[t*8]   = make_float4(acc8[0], acc8[1], acc8[2], acc8[3]);
    *(float4*)&s_gc[t*8+4] = make_float4(acc8[4], acc8[5], acc8[6], acc8[7]);
    #pragma unroll
    for (int gi = 0; gi < 16; ++gi) {  // h1[kk][i] = relu(dist*w1 + b1)
      int e = t + 256*gi;
      h1f[e] = fmaxf(fmaf(s_ndist[e >> 6], de_w1[e & 63], de_b1[e & 63]), 0.f);
    }
    if (t < 8) {
      float s = 0.f;
      for (int d = 0; d < 32; ++d) s = fmaf(bk[t*32+d], s_qv[t*32+d], s);
      s_sb[t] = s;
    }
  }
  __syncthreads();

  // P3: w3g[h][j] (w3-fold) + bg[h] = b3@g  (no sync needed before P4b)
  {
    const int j = t >> 1, sub = t & 1;
    float a0 = 0.f, a1 = 0.f, a2 = 0.f, a3 = 0.f;
    #pragma unroll 8
    for (int c = 0; c < DIM; ++c) {
      float w = b2f(w3T[c*D2 + j]);
      float4 gv = *(const float4*)&s_gc[c*8 + sub*4];
      a0 = fmaf(w, gv.x, a0); a1 = fmaf(w, gv.y, a1);
      a2 = fmaf(w, gv.z, a2); a3 = fmaf(w, gv.w, a3);
    }
    s_w3g[(sub*4+0)*D2 + j] = a0;
    s_w3g[(sub*4+1)*D2 + j] = a1;
    s_w3g[(sub*4+2)*D2 + j] = a2;
    s_w3g[(sub*4+3)*D2 + j] = a3;
    if (t < 8) {
      float s = s_sb[t];
      for (int c = 0; c < DIM; c += 4) {
        float4 b4 = *(const float4*)&de_b3[c];
        const float* gr = &s_gh[t*DIM + c];
        s += b4.x*gr[0] + b4.y*gr[1] + b4.z*gr[2] + b4.w*gr[3];
      }
      s_sb[t] = s;
    }
  }

  // P4b: h2[64][128] = relu(h1 @ de_w2 + b2), bf16 swizzled out
  {
    const int j = t & 127, half = t >> 7;
    const float b2v = de_b2[j];
    float acc[32];
    #pragma unroll
    for (int k = 0; k < 32; ++k) acc[k] = b2v;
    for (int i0 = 0; i0 < D4; i0 += 8) {
      float w8[8];
      #pragma unroll
      for (int u = 0; u < 8; ++u) w8[u] = de_w2[(i0+u)*D2 + j];
      #pragma unroll
      for (int k = 0; k < 32; ++k) {
        const float* hr = &h1f[(half*32 + k)*64 + i0];
        float4 x0 = *(const float4*)hr;
        float4 x1 = *(const float4*)(hr + 4);
        acc[k] = fmaf(x0.x, w8[0], acc[k]); acc[k] = fmaf(x0.y, w8[1], acc[k]);
        acc[k] = fmaf(x0.z, w8[2], acc[k]); acc[k] = fmaf(x0.w, w8[3], acc[k]);
        acc[k] = fmaf(x1.x, w8[4], acc[k]); acc[k] = fmaf(x1.y, w8[5], acc[k]);
        acc[k] = fmaf(x1.z, w8[6], acc[k]); acc[k] = fmaf(x1.w, w8[7], acc[k]);
      }
    }
    #pragma unroll
    for (int k = 0; k < 32; ++k) {
      int r = half*32 + k;
      s_h2[r*D2 + (((j>>3) ^ (r & 15)) << 3) + (j & 7)] = f2b(fmaxf(acc[k], 0.f));
    }
  }
  __syncthreads();   // h2 ready; h1f dead -> F gather may overwrite

  // P4c: gather neighbor features -> F bf16, swizzled
  #pragma unroll 4
  for (int kk = 0; kk < KNNK; ++kk) {
    float f = featB[(size_t)s_nidx[kk]*DIM + t];
    s_F[kk*DIM + (((t>>3) ^ (kk & 31)) << 3) + (t & 7)] = f2b(f);
  }
  __syncthreads();

  // P5: scores[h][kk] = (F@g + h2@w3g + sb[h]) * SCALE
  {
    const int kk = t & 63, ha = t >> 6, hb = ha + 4;
    const int ks = kk & 31, kh = kk & 15;
    float accA = 0.f, accB = 0.f;
    #pragma unroll 2
    for (int c8 = 0; c8 < 32; ++c8) {
      uint4 fv = *(const uint4*)&s_F[kk*DIM + ((c8 ^ ks) << 3)];
      const float* gA = &s_gh[ha*DIM + c8*8];
      const float* gB = &s_gh[hb*DIM + c8*8];
      float4 gA0 = *(const float4*)gA, gA1 = *(const float4*)(gA+4);
      float4 gB0 = *(const float4*)gB, gB1 = *(const float4*)(gB+4);
      float f0 = b2f((u16)(fv.x & 0xffffu)), f1 = b2f((u16)(fv.x >> 16));
      float f2 = b2f((u16)(fv.y & 0xffffu)), f3 = b2f((u16)(fv.y >> 16));
      float f4 = b2f((u16)(fv.z & 0xffffu)), f5 = b2f((u16)(fv.z >> 16));
      float f6 = b2f((u16)(fv.w & 0xffffu)), f7 = b2f((u16)(fv.w >> 16));
      accA = fmaf(f0,gA0.x,accA); accA = fmaf(f1,gA0.y,accA);
      accA = fmaf(f2,gA0.z,accA); accA = fmaf(f3,gA0.w,accA);
      accA = fmaf(f4,gA1.x,accA); accA = fmaf(f5,gA1.y,accA);
      accA = fmaf(f6,gA1.z,accA); accA = fmaf(f7,gA1.w,accA);
      accB = fmaf(f0,gB0.x,accB); accB = fmaf(f1,gB0.y,accB);
      accB = fmaf(f2,gB0.z,accB); accB = fmaf(f3,gB0.w,accB);
      accB = fmaf(f4,gB1.x,accB); accB = fmaf(f5,gB1.y,accB);
      accB = fmaf(f6,gB1.z,accB); accB = fmaf(f7,gB1.w,accB);
    }
    #pragma unroll 2
    for (int j8 = 0; j8 < 16; ++j8) {
      uint4 hv = *(const uint4*)&s_h2[kk*D2 + ((j8 ^ kh) << 3)];
      const float* wA = &s_w3g[ha*D2 + j8*8];
      const float* wB = &s_w3g[hb*D2 + j8*8];
      float4 wA0 = *(const float4*)wA, wA1 = *(const float4*)(wA+4);
      float4 wB0 = *(const float4*)wB, wB1 = *(const float4*)(wB+4);
      float f0 = b2f((u16)(hv.x & 0xffffu)), f1 = b2f((u16)(hv.x >> 16));
      float f2 = b2f((u16)(hv.y & 0xffffu)), f3 = b2f((u16)(hv.y >> 16));
      float f4 = b2f((u16)(hv.z & 0xffffu)), f5 = b2f((u16)(hv.z >> 16));
      float f6 = b2f((u16)(hv.w & 0xffffu)), f7 = b2f((u16)(hv.w >> 16));
      accA = fmaf(f0,wA0.x,accA); accA = fmaf(f1,wA0.y,accA);
      accA = fmaf(f2,wA0.z,accA); accA = fmaf(f3,wA0.w,accA);
      accA = fmaf(f4,wA1.x,accA); accA = fmaf(f5,wA1.y,accA);
      accA = fmaf(f6,wA1.z,accA); accA = fmaf(f7,wA1.w,accA);
      accB = fmaf(f0,wB0.x,accB); accB = fmaf(f1,wB0.y,accB);
      accB = fmaf(f2,wB0.z,accB); accB = fmaf(f3,wB0.w,accB);
      accB = fmaf(f4,wB1.x,accB); accB = fmaf(f5,wB1.y,accB);
      accB = fmaf(f6,wB1.z,accB); accB = fmaf(f7,wB1.w,accB);
    }
    s_sc[ha*KNNK + kk] = (accA + s_sb[ha]) * SCALE_F;
    s_sc[hb*KNNK + kk] = (accB + s_sb[hb]) * SCALE_F;
  }
  __syncthreads();

  // P6: softmax over K=64, per head (32 lanes/head); write attn transposed
  {
    const int h = t >> 5, k2 = t & 31;
    float v0 = s_sc[h*KNNK + k2], v1 = s_sc[h*KNNK + k2 + 32];
    float mx = fmaxf(v0, v1);
    #pragma unroll
    for (int off = 16; off > 0; off >>= 1) mx = fmaxf(mx, __shfl_xor(mx, off, 32));
    float e0 = expf(v0 - mx), e1 = expf(v1 - mx);
    float sm = e0 + e1;
    #pragma unroll
    for (int off = 16; off > 0; off >>= 1) sm += __shfl_xor(sm, off, 32);
    float inv = 1.f / sm;
    s_aT[k2*NHEAD + h]      = e0 * inv;
    s_aT[(k2+32)*NHEAD + h] = e1 * inv;
  }
  __syncthreads();

  // P8a: ah2[h][j] = attn @ h2 -> stored transposed in s_w3g (w3g dead)
  {
    const int j = t & 127, hh = t >> 7;
    float a0 = 0.f, a1 = 0.f, a2 = 0.f, a3 = 0.f;
    #pragma unroll 2
    for (int kk = 0; kk < KNNK; ++kk) {
      float hv = b2f(s_h2[kk*D2 + (((j>>3) ^ (kk & 15)) << 3) + (j & 7)]);
      float4 av = *(const float4*)&s_aT[kk*NHEAD + hh*4];
      a0 = fmaf(av.x, hv, a0); a1 = fmaf(av.y, hv, a1);
      a2 = fmaf(av.z, hv, a2); a3 = fmaf(av.w, hv, a3);
    }
    *(float4*)&s_w3g[j*8 + hh*4] = make_float4(a0, a1, a2, a3);
  }
  __syncthreads();

  // P8b: m[h][c] = attn@F + ah2@w3 + b3 -> into s_gh (g dead)
  {
    float mac[8];
    const float b3v = de_b3[t];
    #pragma unroll
    for (int h = 0; h < 8; ++h) mac[h] = b3v;
    #pragma unroll 2
    for (int kk = 0; kk < KNNK; ++kk) {
      float f = b2f(s_F[kk*DIM + (((t>>3) ^ (kk & 31)) << 3) + (t & 7)]);
      float4 a0 = *(const float4*)&s_aT[kk*NHEAD];
      float4 a1 = *(const float4*)&s_aT[kk*NHEAD + 4];
      mac[0] = fmaf(a0.x, f, mac[0]); mac[1] = fmaf(a0.y, f, mac[1]);
      mac[2] = fmaf(a0.z, f, mac[2]); mac[3] = fmaf(a0.w, f, mac[3]);
      mac[4] = fmaf(a1.x, f, mac[4]); mac[5] = fmaf(a1.y, f, mac[5]);
      mac[6] = fmaf(a1.z, f, mac[6]); mac[7] = fmaf(a1.w, f, mac[7]);
    }
    #pragma unroll 2
    for (int jj = 0; jj < D2; ++jj) {
      float w = de_w3[jj*DIM + t];
      float4 a0 = *(const float4*)&s_w3g[jj*8];
      float4 a1 = *(const float4*)&s_w3g[jj*8 + 4];
      mac[0] = fmaf(a0.x, w, mac[0]); mac[1] = fmaf(a0.y, w, mac[1]);
      mac[2] = fmaf(a0.z, w, mac[2]); mac[3] = fmaf(a0.w, w, mac[3]);
      mac[4] = fmaf(a1.x, w, mac[4]); mac[5] = fmaf(a1.y, w, mac[5]);
      mac[6] = fmaf(a1.z, w, mac[6]); mac[7] = fmaf(a1.w, w, mac[7]);
    }
    #pragma unroll
    for (int h = 0; h < 8; ++h) s_gh[h*DIM + t] = mac[h];
  }
  __syncthreads();

  // P9: ctx[t] = m[h] @ wv[:, t] + bv[t]  (t = h*32+d) -> overwrite q row
  {
    const int h = t >> 5;
    const float* mrow = &s_gh[h*DIM];
    float acc = bv[t];
    for (int c = 0; c < DIM; c += 4) {
      float4 m4 = *(const float4*)&mrow[c];
      acc = fmaf(b2f(wvB[(c+0)*DIM + t]), m4.x, acc);
      acc = fmaf(b2f(wvB[(c+1)*DIM + t]), m4.y, acc);
      acc = fmaf(b2f(wvB[(c+2)*DIM + t]), m4.z, acc);
      acc = fmaf(b2f(wvB[(c+3)*DIM + t]), m4.w, acc);
    }
    qctx[(size_t)bp*DIM + t] = acc;
  }
}

// ---------------------------------------------------------------------------
// Kernel 5: batched tail, 16 rows/block:
//   attended = ctx@wo+bo ; x = [feat,att]@se_w1+b1 ; LN ; relu ; @se_w2+b2
// Reads ctx from d_out rows, overwrites the same rows (row-local, safe).
// ---------------------------------------------------------------------------
__global__ __launch_bounds__(256) void se_kernel(
    const float* __restrict__ features,
    const float* __restrict__ wo,    const float* __restrict__ bo,
    const float* __restrict__ se_w1, const float* __restrict__ se_b1,
    const float* __restrict__ ln_g,  const float* __restrict__ ln_b,
    const float* __restrict__ se_w2, const float* __restrict__ se_b2,
    float* io)
{
  __shared__ __align__(16) float sA[16][DIM];    // ctx, then x
  __shared__ __align__(16) float sB[16][DIM];    // feat, then rx
  __shared__ __align__(16) float sAtt[16][DIM];
  __shared__ float s_mu[16], s_rs[16];
  const int r0 = blockIdx.x * 16, t = threadIdx.x;

  for (int r = 0; r < 16; ++r) {
    sA[r][t] = io[(size_t)(r0+r)*DIM + t];
    sB[r][t] = features[(size_t)(r0+r)*DIM + t];
  }
  __syncthreads();

  // attended
  {
    float acc[16];
    const float bov = bo[t];
    #pragma unroll
    for (int r = 0; r < 16; ++r) acc[r] = bov;
    for (int d = 0; d < DIM; d += 4) {
      float w0 = wo[(d+0)*DIM+t], w1 = wo[(d+1)*DIM+t];
      float w2 = wo[(d+2)*DIM+t], w3v = wo[(d+3)*DIM+t];
      #pragma unroll
      for (int r = 0; r < 16; ++r) {
        float4 f4 = *(const float4*)&sA[r][d];
        acc[r] = fmaf(f4.x, w0, acc[r]); acc[r] = fmaf(f4.y, w1, acc[r]);
        acc[r] = fmaf(f4.z, w2, acc[r]); acc[r] = fmaf(f4.w, w3v, acc[r]);
      }
    }
    #pragma unroll
    for (int r = 0; r < 16; ++r) sAtt[r][t] = acc[r];
  }
  __syncthreads();

  // x = [feat, att] @ se_w1 + b1 -> sA (ctx dead)
  {
    float acc[16];
    const float b1v = se_b1[t];
    #pragma unroll
    for (int r = 0; r < 16; ++r) acc[r] = b1v;
    for (int d = 0; d < DIM; d += 4) {
      float w0 = se_w1[(d+0)*DIM+t], w1 = se_w1[(d+1)*DIM+t];
      float w2 = se_w1[(d+2)*DIM+t], w3v = se_w1[(d+3)*DIM+t];
      #pragma unroll
      for (int r = 0; r < 16; ++r) {
        float4 f4 = *(const float4*)&sB[r][d];
        acc[r] = fmaf(f4.x, w0, acc[r]); acc[r] = fmaf(f4.y, w1, acc[r]);
        acc[r] = fmaf(f4.z, w2, acc[r]); acc[r] = fmaf(f4.w, w3v, acc[r]);
      }
    }
    for (int d = 0; d < DIM; d += 4) {
      float w0 = se_w1[(DIM+d+0)*DIM+t], w1 = se_w1[(DIM+d+1)*DIM+t];
      float w2 = se_w1[(DIM+d+2)*DIM+t], w3v = se_w1[(DIM+d+3)*DIM+t];
      #pragma unroll
      for (int r = 0; r < 16; ++r) {
        float4 f4 = *(const float4*)&sAtt[r][d];
        acc[r] = fmaf(f4.x, w0, acc[r]); acc[r] = fmaf(f4.y, w1, acc[r]);
        acc[r] = fmaf(f4.z, w2, acc[r]); acc[r] = fmaf(f4.w, w3v, acc[r]);
      }
    }
    __syncthreads();   // all sA reads (attended) completed earlier; safe
    #pragma unroll
    for (int r = 0; r < 16; ++r) sA[r][t] = acc[r];
  }
  __syncthreads();

  // LayerNorm stats, 4 rows per wave
  {
    const int w = t >> 6, lane = t & 63;
    for (int i = 0; i < 4; ++i) {
      const int r = w*4 + i;
      float v0 = sA[r][lane], v1 = sA[r][lane+64];
      float v2 = sA[r][lane+128], v3 = sA[r][lane+192];
      float s1 = v0+v1+v2+v3;
      float s2 = v0*v0 + v1*v1 + v2*v2 + v3*v3;
      #pragma unroll
      for (int off = 32; off > 0; off >>= 1) {
        s1 += __shfl_xor(s1, off);
        s2 += __shfl_xor(s2, off);
      }
      if (lane == 0) {
        float mu = s1 * (1.f/256.f);
        s_mu[r] = mu;
        s_rs[r] = 1.f / sqrtf(s2 * (1.f/256.f) - mu*mu + 1e-5f);
      }
    }
  }
  __syncthreads();

  // rx = relu(LN(x)) -> sB (feat dead)
  {
    const float lg = ln_g[t], lb = ln_b[t];
    #pragma unroll
    for (int r = 0; r < 16; ++r)
      sB[r][t] = fmaxf(fmaf((sA[r][t] - s_mu[r]) * s_rs[r], lg, lb), 0.f);
  }
  __syncthreads();

  // out = rx @ se_w2 + b2 -> overwrite io rows
  {
    float acc[16];
    const float b2v = se_b2[t];
    #pragma unroll
    for (int r = 0; r < 16; ++r) acc[r] = b2v;
    for (int d = 0; d < DIM; d += 4) {
      float w0 = se_w2[(d+0)*DIM+t], w1 = se_w2[(d+1)*DIM+t];
      float w2 = se_w2[(d+2)*DIM+t], w3v = se_w2[(d+3)*DIM+t];
      #pragma unroll
      for (int r = 0; r < 16; ++r) {
        float4 f4 = *(const float4*)&sB[r][d];
        acc[r] = fmaf(f4.x, w0, acc[r]); acc[r] = fmaf(f4.y, w1, acc[r]);
        acc[r] = fmaf(f4.z, w2, acc[r]); acc[r] = fmaf(f4.w, w3v, acc[r]);
      }
    }
    #pragma unroll
    for (int r = 0; r < 16; ++r) io[(size_t)(r0+r)*DIM + t] = acc[r];
  }
}

extern "C" void kernel_launch(void* const* d_in, const int* in_sizes, int n_in,
                              void* d_out, int out_size, void* d_ws, size_t ws_size,
                              hipStream_t stream) {
  const float* features = (const float*)d_in[0];
  const float* xyz      = (const float*)d_in[1];
  const float* de_w1 = (const float*)d_in[2];
  const float* de_b1 = (const float*)d_in[3];
  const float* de_w2 = (const float*)d_in[4];
  const float* de_b2 = (const float*)d_in[5];
  const float* de_w3 = (const float*)d_in[6];
  const float* de_b3 = (const float*)d_in[7];
  const float* wq = (const float*)d_in[8];
  const float* bq = (const float*)d_in[9];
  const float* wk = (const float*)d_in[10];
  const float* bk = (const float*)d_in[11];
  const float* wv = (const float*)d_in[12];
  const float* bv = (const float*)d_in[13];
  const float* wo = (const float*)d_in[14];
  const float* bo = (const float*)d_in[15];
  const float* se_w1 = (const float*)d_in[16];
  const float* se_b1 = (const float*)d_in[17];
  const float* ln_g  = (const float*)d_in[18];
  const float* ln_b  = (const float*)d_in[19];
  const float* se_w2 = (const float*)d_in[20];
  const float* se_b2 = (const float*)d_in[21];

  // ws layout (1.8125 MB total, within the previously-proven 2 MB):
  //   [0,1MB)        knn_idx  int[4096][64]
  //   [1MB,1.5MB)    knn_dist f16[4096][64]
  //   [+128KB)       wkT bf16 [256][256]
  //   [+64KB)        w3T bf16 [256][128]
  //   [+128KB)       wvB bf16 [256][256]
  char* wsb = (char*)d_ws;
  int*    knn_idx  = (int*)wsb;
  __half* knn_dist = (__half*)(wsb + (1u<<20));
  u16*    wkT      = (u16*)(wsb + (1u<<20) + (512u<<10));
  u16*    w3T      = (u16*)(wsb + (1u<<20) + (512u<<10) + (128u<<10));
  u16*    wvB      = (u16*)(wsb + (1u<<20) + (512u<<10) + (192u<<10));

  knn_kernel<<<NROWS, 256, 0, stream>>>(xyz, knn_idx, knn_dist);
  prep_kernel<<<640, 256, 0, stream>>>(wk, de_w3, wv, wkT, w3T, wvB);
  qproj_kernel<<<NROWS/16, 256, 0, stream>>>(features, wq, bq, (float*)d_out);
  fused_kernel<<<NROWS, 256, 0, stream>>>(
      features, (float*)d_out, knn_idx, knn_dist, wkT, w3T, wvB,
      de_w1, de_b1, de_w2, de_b2, de_w3, de_b3, bk, bv);
  se_kernel<<<NROWS/16, 256, 0, stream>>>(
      features, wo, bo, se_w1, se_b1, ln_g, ln_b, se_w2, se_b2, (float*)d_out);
}

// Round 2
// 472.058 us; speedup vs baseline: 3.4682x; 1.2547x over previous
//
#include <hip/hip_runtime.h>
#include <hip/hip_bf16.h>
#include <hip/hip_fp16.h>

#define NPOINTS 2048
#define BATCH   2
#define DIM     256
#define D2      128
#define D4      64
#define NHEAD   8
#define HDIM    32
#define KNNK    64
#define NROWS   (BATCH*NPOINTS)
#define SCALE_F 0.17677669529663687f

typedef unsigned short u16;

__device__ __forceinline__ u16 f2h(float f) {
  __half h = __float2half(f); u16 r; __builtin_memcpy(&r, &h, 2); return r;
}
__device__ __forceinline__ float h2f(u16 u) {
  __half h; __builtin_memcpy(&h, &u, 2); return __half2float(h);
}
__device__ __forceinline__ unsigned pkh2(float a, float b) {
  __half2 h = __floats2half2_rn(a, b); unsigned r; __builtin_memcpy(&r, &h, 4); return r;
}
__device__ __forceinline__ float2 uph2(unsigned u) {
  __half2 h; __builtin_memcpy(&h, &u, 4); return __half22float2(h);
}

#if __has_builtin(__builtin_amdgcn_fdot2)
typedef _Float16 hv2_t __attribute__((ext_vector_type(2)));
__device__ __forceinline__ float fdot2f(unsigned a, unsigned b, float c) {
  hv2_t x, y; __builtin_memcpy(&x, &a, 4); __builtin_memcpy(&y, &b, 4);
  return __builtin_amdgcn_fdot2(x, y, c, false);
}
#else
__device__ __forceinline__ float fdot2f(unsigned a, unsigned b, float c) {
  float2 x = uph2(a), y = uph2(b);
  return fmaf(x.x, y.x, fmaf(x.y, y.y, c));
}
#endif

// ---------------------------------------------------------------------------
// Kernel 1: exact KNN (64 smallest of 2048) per point. Distances stored f16.
// ---------------------------------------------------------------------------
__global__ __launch_bounds__(256) void knn_kernel(
    const float* __restrict__ xyz,
    int*    __restrict__ knn_idx,
    __half* __restrict__ knn_dist)
{
  __shared__ float dist[NPOINTS];
  __shared__ unsigned hist[256];
  __shared__ unsigned sh_sel, sh_below;

  const int bp = blockIdx.x;
  const int b  = bp >> 11;
  const int n  = bp & (NPOINTS - 1);
  const int t  = threadIdx.x;
  const float* P = xyz + (size_t)b * NPOINTS * 3;

  const float qx = P[n*3+0], qy = P[n*3+1], qz = P[n*3+2];
  const float r2n = qx*qx + qy*qy + qz*qz;
  for (int m = t; m < NPOINTS; m += 256) {
    float x = P[m*3+0], y = P[m*3+1], z = P[m*3+2];
    float r2m = x*x + y*y + z*z;
    float dt  = x*qx + y*qy + z*qz;
    float sq  = r2n + r2m - 2.f*dt;
    sq = fmaxf(sq, 0.f);
    dist[m] = (sq > 0.f) ? sqrtf(sq) : 0.f;
  }
  __syncthreads();

  unsigned prefix = 0u;
  int k_need = KNNK;
  for (int pass = 0; pass < 4; ++pass) {
    const int shift = 24 - pass*8;
    hist[t] = 0u;
    __syncthreads();
    for (int m = t; m < NPOINTS; m += 256) {
      unsigned bits = __float_as_uint(dist[m]);
      if (((bits >> shift) >> 8) == prefix)
        atomicAdd(&hist[(bits >> shift) & 255u], 1u);
    }
    __syncthreads();
    if (t < 64) {
      unsigned s0 = hist[t*4+0], s1 = hist[t*4+1], s2 = hist[t*4+2], s3 = hist[t*4+3];
      unsigned lsum = s0 + s1 + s2 + s3;
      unsigned scan = lsum;
      #pragma unroll
      for (int off = 1; off < 64; off <<= 1) {
        unsigned o = __shfl_up(scan, off);
        if (t >= off) scan += o;
      }
      unsigned excl = scan - lsum;
      unsigned kk = (unsigned)k_need;
      if (excl < kk && kk <= excl + lsum) {
        unsigned below = excl; int bin = t*4;
        if (kk > below + s0) { below += s0; bin++;
          if (kk > below + s1) { below += s1; bin++;
            if (kk > below + s2) { below += s2; bin++; } } }
        sh_sel = (unsigned)bin; sh_below = below;
      }
    }
    __syncthreads();
    prefix = (prefix << 8) | sh_sel;
    k_need -= (int)sh_below;
    __syncthreads();
  }
  const unsigned Tbits = prefix;
  const int base = KNNK - k_need;

  if (t < 64) {
    int*    oi = knn_idx  + (size_t)bp * KNNK;
    __half* od = knn_dist + (size_t)bp * KNNK;
    int taken = 0;
    for (int c = 0; c < NPOINTS/64; ++c) {
      int m = c*64 + t;
      float dv = dist[m];
      bool lt = (__float_as_uint(dv) < Tbits);
      unsigned long long msk = __ballot(lt);
      int off = __popcll(msk & ((1ull << t) - 1ull));
      if (lt) { oi[taken+off] = m; od[taken+off] = __float2half(dv); }
      taken += __popcll(msk);
    }
    int eq = 0;
    for (int c = 0; c < NPOINTS/64 && eq < k_need; ++c) {
      int m = c*64 + t;
      float dv = dist[m];
      bool e = (__float_as_uint(dv) == Tbits);
      unsigned long long msk = __ballot(e);
      int off = __popcll(msk & ((1ull << t) - 1ull));
      if (e && (eq + off) < k_need) { oi[base+eq+off] = m; od[base+eq+off] = __float2half(dv); }
      eq += __popcll(msk);
    }
  }
}

// ---------------------------------------------------------------------------
// Kernel 2: weight prep — f16-packed copies into ws.
//   wkT2 [d2][c][2]  pairs over d       (P2 g-fold)
//   w3Tf [j][c]      identity copy      (P3 w3g-fold)
//   w3f2 [j2][c][2]  pairs over j       (P8b part2)
//   wvB2 [c2][d][2]  pairs over c       (P9)
//   w2f  [i2][j][2]  pairs over i       (P4b h2 GEMM)
// ---------------------------------------------------------------------------
__global__ __launch_bounds__(256) void prep_kernel(
    const float* __restrict__ wk, const float* __restrict__ de_w3,
    const float* __restrict__ wv, const float* __restrict__ de_w2,
    u16* __restrict__ wkT2, u16* __restrict__ w3Tf, u16* __restrict__ w3f2,
    u16* __restrict__ wvB2, u16* __restrict__ w2f)
{
  int tid = blockIdx.x*256 + threadIdx.x;
  if (tid < 65536) {
    int d = tid >> 8, c = tid & 255;
    wkT2[(d>>1)*512 + c*2 + (d&1)] = f2h(wk[c*DIM + d]);
  } else if (tid < 98304) {
    int o = tid - 65536;
    w3Tf[o] = f2h(de_w3[o]);                       // de_w3 is [128][256] row-major
  } else if (tid < 131072) {
    int o = tid - 98304; int j = o >> 8, c = o & 255;
    w3f2[(j>>1)*512 + c*2 + (j&1)] = f2h(de_w3[j*DIM + c]);
  } else if (tid < 196608) {
    int o = tid - 131072; int c = o >> 8, d = o & 255;
    wvB2[(c>>1)*512 + d*2 + (c&1)] = f2h(wv[c*DIM + d]);
  } else if (tid < 204800) {
    int o = tid - 196608; int i = o >> 7, j = o & 127;
    w2f[(i>>1)*256 + j*2 + (i&1)] = f2h(de_w2[i*D2 + j]);
  }
}

// ---------------------------------------------------------------------------
// Kernel 3: batched q projection, 16 rows/block. q -> d_out (scratch).
// ---------------------------------------------------------------------------
__global__ __launch_bounds__(256) void qproj_kernel(
    const float* __restrict__ features, const float* __restrict__ wq,
    const float* __restrict__ bq, float* __restrict__ qout)
{
  __shared__ __align__(16) float sf[16][DIM];
  const int r0 = blockIdx.x * 16, t = threadIdx.x;
  for (int r = 0; r < 16; ++r) sf[r][t] = features[(size_t)(r0+r)*DIM + t];
  __syncthreads();
  float acc[16];
  const float bqv = bq[t];
  #pragma unroll
  for (int r = 0; r < 16; ++r) acc[r] = bqv;
  for (int d = 0; d < DIM; d += 4) {
    float w0 = wq[(d+0)*DIM+t], w1 = wq[(d+1)*DIM+t];
    float w2 = wq[(d+2)*DIM+t], w3v = wq[(d+3)*DIM+t];
    #pragma unroll
    for (int r = 0; r < 16; ++r) {
      float4 f4 = *(const float4*)&sf[r][d];
      acc[r] = fmaf(f4.x, w0, acc[r]); acc[r] = fmaf(f4.y, w1, acc[r]);
      acc[r] = fmaf(f4.z, w2, acc[r]); acc[r] = fmaf(f4.w, w3v, acc[r]);
    }
  }
  #pragma unroll
  for (int r = 0; r < 16; ++r) qout[(size_t)(r0+r)*DIM + t] = acc[r];
}

// ---------------------------------------------------------------------------
// Kernel 4: fused per-point pipeline, f16-packed LDS + v_dot2 everywhere.
// All per-point LDS traffic is b128-granular f16 pairs; weights come from
// global (scalar cache / L2), keeping the single LDS pipe off the critical
// path.  attn and m stay f32 for accuracy.
// ---------------------------------------------------------------------------
__global__ __launch_bounds__(256) void fused_kernel(
    const float* __restrict__ features,
    float* __restrict__ qctx,                       // d_out: q in, ctx out
    const int*    __restrict__ knn_idx,
    const __half* __restrict__ knn_dist,
    const u16* __restrict__ wkT2, const u16* __restrict__ w3Tf,
    const u16* __restrict__ w3f2, const u16* __restrict__ wvB2,
    const u16* __restrict__ w2f,
    const float* __restrict__ de_w1, const float* __restrict__ de_b1,
    const float* __restrict__ de_b2, const float* __restrict__ de_b3,
    const float* __restrict__ bk,    const float* __restrict__ bv)
{
  // 62.5 KB total -> 2 blocks/CU
  __shared__ __align__(16) unsigned s_F32[KNNK*D2];   // 32KB F f16 pairs (swizzled); first 8KB = h1p
  __shared__ __align__(16) unsigned s_h2_32[KNNK*64]; // 16KB h2 f16 pairs (swizzled)
  __shared__ __align__(16) float    s_gm[2048];       // 8KB: ghb f16[8][256] (4KB) -> m f32[8][256]
  __shared__ __align__(16) float    s_d[1024];        // 4KB: w3gb f16(2KB)+sc f32(2KB) -> ah2p u32(2KB)
  __shared__ __align__(16) float    s_aT[KNNK*NHEAD]; // 2KB attn f32 [kk][h]
  __shared__ int   s_nidx[KNNK];
  __shared__ float s_ndist[KNNK];
  __shared__ float s_sb[NHEAD];

  unsigned* h1p    = s_F32;               // u32[32][64]: h1 pairs [i2][k]
  u16*      s_ghb  = (u16*)s_gm;          // f16 [8][256]
  u16*      s_w3gb = (u16*)s_d;           // f16 [8][128]
  float*    s_sc   = s_d + 512;           // f32 [8][64]
  unsigned* s_ah2p = (unsigned*)s_d;      // u32 [64][8]  (after P6)
  float*    s_m    = s_gm;                // f32 [8][256] (after P5)

  const int bp = blockIdx.x;
  const int b  = bp >> 11;
  const int t  = threadIdx.x;
  const float* featB = features + (size_t)b * NPOINTS * DIM;
  const float* qrow  = qctx + (size_t)bp * DIM;     // wave-uniform -> s_load

  // ---- P0 ----
  if (t < KNNK) {
    s_nidx[t]  = knn_idx[(size_t)bp*KNNK + t];
    s_ndist[t] = __half2float(knn_dist[(size_t)bp*KNNK + t]);
  }
  __syncthreads();

  // ---- phase A: g-fold (P2) + h1 pairs (P4bi) + sb=q.bk ----
  {
    const unsigned* wk2 = (const unsigned*)wkT2;
    #pragma unroll
    for (int h = 0; h < NHEAD; ++h) {
      float a = 0.f;
      #pragma unroll
      for (int dg = 0; dg < 16; ++dg) {
        const int d2 = h*16 + dg;
        a = fdot2f(wk2[d2*256 + t], pkh2(qrow[2*d2], qrow[2*d2+1]), a);
      }
      s_ghb[h*256 + t] = f2h(a);
    }
    const int k = t & 63;
    const float dk = s_ndist[k];
    #pragma unroll
    for (int g = 0; g < 8; ++g) {
      const int i2 = (t>>6)*8 + g, i = 2*i2;
      float h1a = fmaxf(fmaf(dk, de_w1[i],   de_b1[i]),   0.f);
      float h1b = fmaxf(fmaf(dk, de_w1[i+1], de_b1[i+1]), 0.f);
      h1p[i2*64 + k] = pkh2(h1a, h1b);
    }
    if (t < NHEAD) {
      float s = 0.f;
      for (int d = 0; d < HDIM; ++d) s = fmaf(bk[t*HDIM+d], qrow[t*HDIM+d], s);
      s_sb[t] = s;
    }
  }
  __syncthreads();

  // ---- phase B: w3g-fold + sb += b3.g (P3)  and  h2 GEMM (P4bii) ----
  {
    const int j = t & 127, h0 = (t >> 7) * 4;
    float a0=0.f, a1=0.f, a2=0.f, a3=0.f;
    const uint4* w3r = (const uint4*)(w3Tf + (size_t)j*256);
    #pragma unroll 4
    for (int c8 = 0; c8 < 32; ++c8) {
      uint4 wv4 = w3r[c8];
      uint4 gv;
      gv = *(const uint4*)(s_ghb + (h0+0)*256 + c8*8);
      a0 = fdot2f(wv4.x, gv.x, a0); a0 = fdot2f(wv4.y, gv.y, a0);
      a0 = fdot2f(wv4.z, gv.z, a0); a0 = fdot2f(wv4.w, gv.w, a0);
      gv = *(const uint4*)(s_ghb + (h0+1)*256 + c8*8);
      a1 = fdot2f(wv4.x, gv.x, a1); a1 = fdot2f(wv4.y, gv.y, a1);
      a1 = fdot2f(wv4.z, gv.z, a1); a1 = fdot2f(wv4.w, gv.w, a1);
      gv = *(const uint4*)(s_ghb + (h0+2)*256 + c8*8);
      a2 = fdot2f(wv4.x, gv.x, a2); a2 = fdot2f(wv4.y, gv.y, a2);
      a2 = fdot2f(wv4.z, gv.z, a2); a2 = fdot2f(wv4.w, gv.w, a2);
      gv = *(const uint4*)(s_ghb + (h0+3)*256 + c8*8);
      a3 = fdot2f(wv4.x, gv.x, a3); a3 = fdot2f(wv4.y, gv.y, a3);
      a3 = fdot2f(wv4.z, gv.z, a3); a3 = fdot2f(wv4.w, gv.w, a3);
    }
    s_w3gb[(h0+0)*128 + j] = f2h(a0);
    s_w3gb[(h0+1)*128 + j] = f2h(a1);
    s_w3gb[(h0+2)*128 + j] = f2h(a2);
    s_w3gb[(h0+3)*128 + j] = f2h(a3);
    if (t < NHEAD) {
      float s = s_sb[t];
      const uint4* gr = (const uint4*)(s_ghb + t*256);
      for (int c8 = 0; c8 < 32; ++c8) {
        uint4 gv = gr[c8];
        float4 bA = *(const float4*)&de_b3[c8*8];
        float4 bB = *(const float4*)&de_b3[c8*8+4];
        float2 p;
        p = uph2(gv.x); s = fmaf(p.x, bA.x, s); s = fmaf(p.y, bA.y, s);
        p = uph2(gv.y); s = fmaf(p.x, bA.z, s); s = fmaf(p.y, bA.w, s);
        p = uph2(gv.z); s = fmaf(p.x, bB.x, s); s = fmaf(p.y, bB.y, s);
        p = uph2(gv.w); s = fmaf(p.x, bB.z, s); s = fmaf(p.y, bB.w, s);
      }
      s_sb[t] = s;
    }
    // P4bii: h2[64][128] = relu(h1 @ w2 + b2), register tile 8k x 4j
    const int kt = t >> 5, jt = t & 31, kk0 = kt*8;
    float acc[8][4];
    float4 b2v = *(const float4*)&de_b2[jt*4];
    #pragma unroll
    for (int r = 0; r < 8; ++r) {
      acc[r][0]=b2v.x; acc[r][1]=b2v.y; acc[r][2]=b2v.z; acc[r][3]=b2v.w;
    }
    const unsigned* w2_32 = (const unsigned*)w2f;
    #pragma unroll 4
    for (int i2 = 0; i2 < 32; ++i2) {
      uint4 ha4 = *(const uint4*)(h1p + i2*64 + kk0);
      uint4 hb4 = *(const uint4*)(h1p + i2*64 + kk0 + 4);
      uint4 w4  = *(const uint4*)(w2_32 + i2*128 + jt*4);
      acc[0][0]=fdot2f(ha4.x,w4.x,acc[0][0]); acc[0][1]=fdot2f(ha4.x,w4.y,acc[0][1]);
      acc[0][2]=fdot2f(ha4.x,w4.z,acc[0][2]); acc[0][3]=fdot2f(ha4.x,w4.w,acc[0][3]);
      acc[1][0]=fdot2f(ha4.y,w4.x,acc[1][0]); acc[1][1]=fdot2f(ha4.y,w4.y,acc[1][1]);
      acc[1][2]=fdot2f(ha4.y,w4.z,acc[1][2]); acc[1][3]=fdot2f(ha4.y,w4.w,acc[1][3]);
      acc[2][0]=fdot2f(ha4.z,w4.x,acc[2][0]); acc[2][1]=fdot2f(ha4.z,w4.y,acc[2][1]);
      acc[2][2]=fdot2f(ha4.z,w4.z,acc[2][2]); acc[2][3]=fdot2f(ha4.z,w4.w,acc[2][3]);
      acc[3][0]=fdot2f(ha4.w,w4.x,acc[3][0]); acc[3][1]=fdot2f(ha4.w,w4.y,acc[3][1]);
      acc[3][2]=fdot2f(ha4.w,w4.z,acc[3][2]); acc[3][3]=fdot2f(ha4.w,w4.w,acc[3][3]);
      acc[4][0]=fdot2f(hb4.x,w4.x,acc[4][0]); acc[4][1]=fdot2f(hb4.x,w4.y,acc[4][1]);
      acc[4][2]=fdot2f(hb4.x,w4.z,acc[4][2]); acc[4][3]=fdot2f(hb4.x,w4.w,acc[4][3]);
      acc[5][0]=fdot2f(hb4.y,w4.x,acc[5][0]); acc[5][1]=fdot2f(hb4.y,w4.y,acc[5][1]);
      acc[5][2]=fdot2f(hb4.y,w4.z,acc[5][2]); acc[5][3]=fdot2f(hb4.y,w4.w,acc[5][3]);
      acc[6][0]=fdot2f(hb4.z,w4.x,acc[6][0]); acc[6][1]=fdot2f(hb4.z,w4.y,acc[6][1]);
      acc[6][2]=fdot2f(hb4.z,w4.z,acc[6][2]); acc[6][3]=fdot2f(hb4.z,w4.w,acc[6][3]);
      acc[7][0]=fdot2f(hb4.w,w4.x,acc[7][0]); acc[7][1]=fdot2f(hb4.w,w4.y,acc[7][1]);
      acc[7][2]=fdot2f(hb4.w,w4.z,acc[7][2]); acc[7][3]=fdot2f(hb4.w,w4.w,acc[7][3]);
    }
    #pragma unroll
    for (int r = 0; r < 8; ++r) {
      const int kk = kk0 + r;
      unsigned lo = pkh2(fmaxf(acc[r][0],0.f), fmaxf(acc[r][1],0.f));
      unsigned hi = pkh2(fmaxf(acc[r][2],0.f), fmaxf(acc[r][3],0.f));
      *(uint2*)(s_h2_32 + kk*64 + (((jt>>1)^(kk&15))<<2) + (jt&1)*2) = make_uint2(lo, hi);
    }
  }
  __syncthreads();   // h1p dead -> F gather may overwrite

  // ---- phase C: gather neighbor features -> F f16 pairs, swizzled ----
  {
    const int cc = (t & 127) * 2, half = t >> 7;
    #pragma unroll 4
    for (int p = 0; p < 32; ++p) {
      const int kk = p*2 + half;
      const int row = s_nidx[kk];
      float2 f2 = *(const float2*)&featB[(size_t)row*DIM + cc];
      s_F32[kk*128 + (((cc>>3)^(kk&31))<<2) + ((cc&7)>>1)] = pkh2(f2.x, f2.y);
    }
  }
  __syncthreads();

  // ---- P5: scores[h][kk] = (F.g + h2.w3g + sb[h]) * SCALE ----
  {
    const int kk = t & 63, ha = t >> 6, hb = ha + 4;
    const int ks = kk & 31, kh = kk & 15;
    float accA = 0.f, accB = 0.f;
    const uint4* Fr = (const uint4*)(s_F32 + kk*128);
    const uint4* GA = (const uint4*)(s_ghb + ha*256);
    const uint4* GB = (const uint4*)(s_ghb + hb*256);
    #pragma unroll 4
    for (int c8 = 0; c8 < 32; ++c8) {
      uint4 fv = Fr[c8 ^ ks];
      uint4 ga = GA[c8], gb = GB[c8];
      accA = fdot2f(fv.x, ga.x, accA); accA = fdot2f(fv.y, ga.y, accA);
      accA = fdot2f(fv.z, ga.z, accA); accA = fdot2f(fv.w, ga.w, accA);
      accB = fdot2f(fv.x, gb.x, accB); accB = fdot2f(fv.y, gb.y, accB);
      accB = fdot2f(fv.z, gb.z, accB); accB = fdot2f(fv.w, gb.w, accB);
    }
    const uint4* Hr = (const uint4*)(s_h2_32 + kk*64);
    const uint4* WA = (const uint4*)(s_w3gb + ha*128);
    const uint4* WB = (const uint4*)(s_w3gb + hb*128);
    #pragma unroll 4
    for (int j8 = 0; j8 < 16; ++j8) {
      uint4 hv = Hr[j8 ^ kh];
      uint4 wa = WA[j8], wb = WB[j8];
      accA = fdot2f(hv.x, wa.x, accA); accA = fdot2f(hv.y, wa.y, accA);
      accA = fdot2f(hv.z, wa.z, accA); accA = fdot2f(hv.w, wa.w, accA);
      accB = fdot2f(hv.x, wb.x, accB); accB = fdot2f(hv.y, wb.y, accB);
      accB = fdot2f(hv.z, wb.z, accB); accB = fdot2f(hv.w, wb.w, accB);
    }
    s_sc[ha*64 + kk] = (accA + s_sb[ha]) * SCALE_F;
    s_sc[hb*64 + kk] = (accB + s_sb[hb]) * SCALE_F;
  }
  __syncthreads();

  // ---- P6: softmax over K=64 per head; attn stays f32 ----
  {
    const int h = t >> 5, k2 = t & 31;
    float v0 = s_sc[h*64 + k2], v1 = s_sc[h*64 + k2 + 32];
    float mx = fmaxf(v0, v1);
    #pragma unroll
    for (int off = 16; off > 0; off >>= 1) mx = fmaxf(mx, __shfl_xor(mx, off, 32));
    float e0 = expf(v0 - mx), e1 = expf(v1 - mx);
    float sm = e0 + e1;
    #pragma unroll
    for (int off = 16; off > 0; off >>= 1) sm += __shfl_xor(sm, off, 32);
    float inv = 1.f / sm;
    s_aT[k2*NHEAD + h]      = e0 * inv;
    s_aT[(k2+32)*NHEAD + h] = e1 * inv;
  }
  __syncthreads();

  // ---- P8a: ah2 = attn @ h2, output packed f16 j-pairs [j2][h] ----
  {
    const int jj2 = t & 63, hp = t >> 6;
    const int j = jj2*2;
    float a00=0.f, a01=0.f, a10=0.f, a11=0.f;
    #pragma unroll 4
    for (int kk = 0; kk < KNNK; ++kk) {
      unsigned hpw = s_h2_32[kk*64 + (((j>>3)^(kk&15))<<2) + ((j&7)>>1)];
      float2 hv = uph2(hpw);
      float2 av = *(const float2*)&s_aT[kk*NHEAD + hp*2];
      a00 = fmaf(av.x, hv.x, a00); a01 = fmaf(av.x, hv.y, a01);
      a10 = fmaf(av.y, hv.x, a10); a11 = fmaf(av.y, hv.y, a11);
    }
    s_ah2p[jj2*8 + hp*2]     = pkh2(a00, a01);
    s_ah2p[jj2*8 + hp*2 + 1] = pkh2(a10, a11);
  }
  __syncthreads();

  // ---- P8b: m[h][c] = attn@F + ah2@w3 + b3 (f32) ----
  {
    const int h = t >> 5, ct = t & 31;
    float mac[8];
    float4 b3a = *(const float4*)&de_b3[ct*8];
    float4 b3b = *(const float4*)&de_b3[ct*8+4];
    mac[0]=b3a.x; mac[1]=b3a.y; mac[2]=b3a.z; mac[3]=b3a.w;
    mac[4]=b3b.x; mac[5]=b3b.y; mac[6]=b3b.z; mac[7]=b3b.w;
    #pragma unroll 2
    for (int kk = 0; kk < KNNK; ++kk) {
      uint4 fv = *((const uint4*)(s_F32 + kk*128) + (ct ^ (kk&31)));
      float a = s_aT[kk*NHEAD + h];
      float2 p;
      p = uph2(fv.x); mac[0] = fmaf(a, p.x, mac[0]); mac[1] = fmaf(a, p.y, mac[1]);
      p = uph2(fv.y); mac[2] = fmaf(a, p.x, mac[2]); mac[3] = fmaf(a, p.y, mac[3]);
      p = uph2(fv.z); mac[4] = fmaf(a, p.x, mac[4]); mac[5] = fmaf(a, p.y, mac[5]);
      p = uph2(fv.w); mac[6] = fmaf(a, p.x, mac[6]); mac[7] = fmaf(a, p.y, mac[7]);
    }
    const unsigned* w3_32 = (const unsigned*)w3f2;
    #pragma unroll 2
    for (int jj2 = 0; jj2 < 64; ++jj2) {
      unsigned ap = s_ah2p[jj2*8 + h];
      const uint4* wr = (const uint4*)(w3_32 + jj2*256 + ct*8);
      uint4 w0 = wr[0], w1 = wr[1];
      mac[0] = fdot2f(w0.x, ap, mac[0]); mac[1] = fdot2f(w0.y, ap, mac[1]);
      mac[2] = fdot2f(w0.z, ap, mac[2]); mac[3] = fdot2f(w0.w, ap, mac[3]);
      mac[4] = fdot2f(w1.x, ap, mac[4]); mac[5] = fdot2f(w1.y, ap, mac[5]);
      mac[6] = fdot2f(w1.z, ap, mac[6]); mac[7] = fdot2f(w1.w, ap, mac[7]);
    }
    *(float4*)&s_m[h*256 + ct*8]     = make_float4(mac[0], mac[1], mac[2], mac[3]);
    *(float4*)&s_m[h*256 + ct*8 + 4] = make_float4(mac[4], mac[5], mac[6], mac[7]);
  }
  __syncthreads();

  // ---- P9: ctx[t] = m[h] . wv[:, t] + bv[t]  (t = h*32+d) ----
  {
    const int h = t >> 5;
    const float* mr = s_m + h*256;
    const unsigned* wv_32 = (const unsigned*)wvB2;
    float acc = bv[t];
    #pragma unroll 4
    for (int c4 = 0; c4 < 64; ++c4) {
      float4 m4 = *(const float4*)(mr + c4*4);
      float2 wa = uph2(wv_32[(c4*2)*256 + t]);
      float2 wb = uph2(wv_32[(c4*2+1)*256 + t]);
      acc = fmaf(wa.x, m4.x, acc); acc = fmaf(wa.y, m4.y, acc);
      acc = fmaf(wb.x, m4.z, acc); acc = fmaf(wb.y, m4.w, acc);
    }
    qctx[(size_t)bp*DIM + t] = acc;
  }
}

// ---------------------------------------------------------------------------
// Kernel 5: batched tail, 16 rows/block (unchanged).
// ---------------------------------------------------------------------------
__global__ __launch_bounds__(256) void se_kernel(
    const float* __restrict__ features,
    const float* __restrict__ wo,    const float* __restrict__ bo,
    const float* __restrict__ se_w1, const float* __restrict__ se_b1,
    const float* __restrict__ ln_g,  const float* __restrict__ ln_b,
    const float* __restrict__ se_w2, const float* __restrict__ se_b2,
    float* io)
{
  __shared__ __align__(16) float sA[16][DIM];
  __shared__ __align__(16) float sB[16][DIM];
  __shared__ __align__(16) float sAtt[16][DIM];
  __shared__ float s_mu[16], s_rs[16];
  const int r0 = blockIdx.x * 16, t = threadIdx.x;

  for (int r = 0; r < 16; ++r) {
    sA[r][t] = io[(size_t)(r0+r)*DIM + t];
    sB[r][t] = features[(size_t)(r0+r)*DIM + t];
  }
  __syncthreads();

  {
    float acc[16];
    const float bov = bo[t];
    #pragma unroll
    for (int r = 0; r < 16; ++r) acc[r] = bov;
    for (int d = 0; d < DIM; d += 4) {
      float w0 = wo[(d+0)*DIM+t], w1 = wo[(d+1)*DIM+t];
      float w2 = wo[(d+2)*DIM+t], w3v = wo[(d+3)*DIM+t];
      #pragma unroll
      for (int r = 0; r < 16; ++r) {
        float4 f4 = *(const float4*)&sA[r][d];
        acc[r] = fmaf(f4.x, w0, acc[r]); acc[r] = fmaf(f4.y, w1, acc[r]);
        acc[r] = fmaf(f4.z, w2, acc[r]); acc[r] = fmaf(f4.w, w3v, acc[r]);
      }
    }
    #pragma unroll
    for (int r = 0; r < 16; ++r) sAtt[r][t] = acc[r];
  }
  __syncthreads();

  {
    float acc[16];
    const float b1v = se_b1[t];
    #pragma unroll
    for (int r = 0; r < 16; ++r) acc[r] = b1v;
    for (int d = 0; d < DIM; d += 4) {
      float w0 = se_w1[(d+0)*DIM+t], w1 = se_w1[(d+1)*DIM+t];
      float w2 = se_w1[(d+2)*DIM+t], w3v = se_w1[(d+3)*DIM+t];
      #pragma unroll
      for (int r = 0; r < 16; ++r) {
        float4 f4 = *(const float4*)&sB[r][d];
        acc[r] = fmaf(f4.x, w0, acc[r]); acc[r] = fmaf(f4.y, w1, acc[r]);
        acc[r] = fmaf(f4.z, w2, acc[r]); acc[r] = fmaf(f4.w, w3v, acc[r]);
      }
    }
    for (int d = 0; d < DIM; d += 4) {
      float w0 = se_w1[(DIM+d+0)*DIM+t], w1 = se_w1[(DIM+d+1)*DIM+t];
      float w2 = se_w1[(DIM+d+2)*DIM+t], w3v = se_w1[(DIM+d+3)*DIM+t];
      #pragma unroll
      for (int r = 0; r < 16; ++r) {
        float4 f4 = *(const float4*)&sAtt[r][d];
        acc[r] = fmaf(f4.x, w0, acc[r]); acc[r] = fmaf(f4.y, w1, acc[r]);
        acc[r] = fmaf(f4.z, w2, acc[r]); acc[r] = fmaf(f4.w, w3v, acc[r]);
      }
    }
    __syncthreads();
    #pragma unroll
    for (int r = 0; r < 16; ++r) sA[r][t] = acc[r];
  }
  __syncthreads();

  {
    const int w = t >> 6, lane = t & 63;
    for (int i = 0; i < 4; ++i) {
      const int r = w*4 + i;
      float v0 = sA[r][lane], v1 = sA[r][lane+64];
      float v2 = sA[r][lane+128], v3 = sA[r][lane+192];
      float s1 = v0+v1+v2+v3;
      float s2 = v0*v0 + v1*v1 + v2*v2 + v3*v3;
      #pragma unroll
      for (int off = 32; off > 0; off >>= 1) {
        s1 += __shfl_xor(s1, off);
        s2 += __shfl_xor(s2, off);
      }
      if (lane == 0) {
        float mu = s1 * (1.f/256.f);
        s_mu[r] = mu;
        s_rs[r] = 1.f / sqrtf(s2 * (1.f/256.f) - mu*mu + 1e-5f);
      }
    }
  }
  __syncthreads();

  {
    const float lg = ln_g[t], lb = ln_b[t];
    #pragma unroll
    for (int r = 0; r < 16; ++r)
      sB[r][t] = fmaxf(fmaf((sA[r][t] - s_mu[r]) * s_rs[r], lg, lb), 0.f);
  }
  __syncthreads();

  {
    float acc[16];
    const float b2v = se_b2[t];
    #pragma unroll
    for (int r = 0; r < 16; ++r) acc[r] = b2v;
    for (int d = 0; d < DIM; d += 4) {
      float w0 = se_w2[(d+0)*DIM+t], w1 = se_w2[(d+1)*DIM+t];
      float w2 = se_w2[(d+2)*DIM+t], w3v = se_w2[(d+3)*DIM+t];
      #pragma unroll
      for (int r = 0; r < 16; ++r) {
        float4 f4 = *(const float4*)&sB[r][d];
        acc[r] = fmaf(f4.x, w0, acc[r]); acc[r] = fmaf(f4.y, w1, acc[r]);
        acc[r] = fmaf(f4.z, w2, acc[r]); acc[r] = fmaf(f4.w, w3v, acc[r]);
      }
    }
    #pragma unroll
    for (int r = 0; r < 16; ++r) io[(size_t)(r0+r)*DIM + t] = acc[r];
  }
}

extern "C" void kernel_launch(void* const* d_in, const int* in_sizes, int n_in,
                              void* d_out, int out_size, void* d_ws, size_t ws_size,
                              hipStream_t stream) {
  const float* features = (const float*)d_in[0];
  const float* xyz      = (const float*)d_in[1];
  const float* de_w1 = (const float*)d_in[2];
  const float* de_b1 = (const float*)d_in[3];
  const float* de_w2 = (const float*)d_in[4];
  const float* de_b2 = (const float*)d_in[5];
  const float* de_w3 = (const float*)d_in[6];
  const float* de_b3 = (const float*)d_in[7];
  const float* wq = (const float*)d_in[8];
  const float* bq = (const float*)d_in[9];
  const float* wk = (const float*)d_in[10];
  const float* bk = (const float*)d_in[11];
  const float* wv = (const float*)d_in[12];
  const float* bv = (const float*)d_in[13];
  const float* wo = (const float*)d_in[14];
  const float* bo = (const float*)d_in[15];
  const float* se_w1 = (const float*)d_in[16];
  const float* se_b1 = (const float*)d_in[17];
  const float* ln_g  = (const float*)d_in[18];
  const float* ln_b  = (const float*)d_in[19];
  const float* se_w2 = (const float*)d_in[20];
  const float* se_b2 = (const float*)d_in[21];

  // ws layout (1.9375 MB total):
  //   [0,1MB)    knn_idx int[4096][64]
  //   [+512KB)   knn_dist f16[4096][64]
  //   [+128KB)   wkT2  f16 pairs
  //   [+64KB)    w3Tf  f16 [j][c]
  //   [+64KB)    w3f2  f16 pairs
  //   [+128KB)   wvB2  f16 pairs
  //   [+16KB)    w2f   f16 pairs
  char* wsb = (char*)d_ws;
  int*    knn_idx  = (int*)wsb;
  __half* knn_dist = (__half*)(wsb + (1u<<20));
  u16* wkT2 = (u16*)(wsb + 1536u*1024u);
  u16* w3Tf = (u16*)(wsb + 1536u*1024u + 128u*1024u);
  u16* w3f2 = (u16*)(wsb + 1536u*1024u + 192u*1024u);
  u16* wvB2 = (u16*)(wsb + 1536u*1024u + 256u*1024u);
  u16* w2f  = (u16*)(wsb + 1536u*1024u + 384u*1024u);

  knn_kernel<<<NROWS, 256, 0, stream>>>(xyz, knn_idx, knn_dist);
  prep_kernel<<<800, 256, 0, stream>>>(wk, de_w3, wv, de_w2,
                                       wkT2, w3Tf, w3f2, wvB2, w2f);
  qproj_kernel<<<NROWS/16, 256, 0, stream>>>(features, wq, bq, (float*)d_out);
  fused_kernel<<<NROWS, 256, 0, stream>>>(
      features, (float*)d_out, knn_idx, knn_dist,
      wkT2, w3Tf, w3f2, wvB2, w2f,
      de_w1, de_b1, de_b2, de_b3, bk, bv);
  se_kernel<<<NROWS/16, 256, 0, stream>>>(
      features, wo, bo, se_w1, se_b1, ln_g, ln_b, se_w2, se_b2, (float*)d_out);
}